// Round 1
// baseline (308.016 us; speedup 1.0000x reference)
//
#include <hip/hip_runtime.h>

// out[n,o,z,y,x] = b[o] + sum_{kd, d=z+kd-2 in [0,10)} sum_{kh,kw}
//                  x[n,d,y+kh-2,x+kw-2] * W[o,d,kd,kh,kw]
// Diagonal-embed Conv3d == per-z sum of <=5 2D 5x5 convs.

#define TILE_ROWS 8
#define LDS_ROWS  12      // TILE_ROWS + 4 halo
#define LDS_W     132     // 128 + 4 halo (16B-aligned rows: 132*4B = 528B)
#define BLOCK     256

__global__ __launch_bounds__(BLOCK, 4)
void conv3d_diag_kernel(const float* __restrict__ x,     // [32,10,128,128]
                        const float* __restrict__ Wt,    // [10,10,5,5,5] OIDHW
                        const float* __restrict__ bias,  // [10]
                        float* __restrict__ out)         // [32,10,10,128,128]
{
    __shared__ float lds[LDS_ROWS * LDS_W];

    const int tid  = threadIdx.x;
    const int tile = blockIdx.x;   // 0..15  (row tile)
    const int z    = blockIdx.y;   // 0..9   (output depth)
    const int n    = blockIdx.z;   // 0..31  (batch)

    const int y0 = tile * TILE_ROWS;
    const int tx = tid & 31;       // 0..31 -> 4-wide column group
    const int ty = tid >> 5;       // 0..7  -> row within tile
    const int x0 = tx << 2;        // output column base
    const int y  = y0 + ty;        // output row

    float acc[10][4];
    #pragma unroll
    for (int o = 0; o < 10; ++o)
        #pragma unroll
        for (int p = 0; p < 4; ++p) acc[o][p] = 0.f;

    const float* xn = x + (size_t)n * (10 * 128 * 128);

    #pragma unroll 1
    for (int kd = 0; kd < 5; ++kd) {
        const int d = z + kd - 2;          // input channel (block-uniform)
        if (d < 0 || d >= 10) continue;    // uniform branch: no divergence
        const float* xp = xn + d * (128 * 128);

        __syncthreads();   // protect LDS from previous iteration's readers
        // Stage rows [y0-2, y0+9] x cols [-2, 129] into LDS, zero-padded.
        for (int e = tid; e < LDS_ROWS * LDS_W; e += BLOCK) {
            const int r  = e / LDS_W;
            const int c  = e - r * LDS_W;
            const int gr = y0 - 2 + r;
            const int gc = c - 2;
            float v = 0.f;
            if ((unsigned)gr < 128u && (unsigned)gc < 128u)
                v = xp[gr * 128 + gc];
            lds[e] = v;
        }
        __syncthreads();

        #pragma unroll 1
        for (int kh = 0; kh < 5; ++kh) {
            // Weights W[o, d, kd, kh, kw]; address uniform across block ->
            // compiler emits scalar loads (scalar pipe, off the VALU).
            const float* wp = Wt + (size_t)(d * 125 + kd * 25 + kh * 5);
            float wv[10][5];
            #pragma unroll
            for (int o = 0; o < 10; ++o)
                #pragma unroll
                for (int kw = 0; kw < 5; ++kw)
                    wv[o][kw] = wp[o * 1250 + kw];

            // 8 input floats covering cols x0-2 .. x0+5 (halo offset +2):
            // LDS index (ty+kh)*132 + x0 is float4-aligned.
            const float* lp = &lds[(ty + kh) * LDS_W + x0];
            const float4 rlo = *(const float4*)(lp);
            const float4 rhi = *(const float4*)(lp + 4);
            const float r[8] = {rlo.x, rlo.y, rlo.z, rlo.w,
                                rhi.x, rhi.y, rhi.z, rhi.w};

            #pragma unroll
            for (int kw = 0; kw < 5; ++kw)
                #pragma unroll
                for (int o = 0; o < 10; ++o)
                    #pragma unroll
                    for (int p = 0; p < 4; ++p)
                        acc[o][p] += r[p + kw] * wv[o][kw];
        }
    }

    // Epilogue: add bias, store 10 coalesced float4 rows.
    #pragma unroll
    for (int o = 0; o < 10; ++o) {
        const float bo = bias[o];
        const float4 v = make_float4(acc[o][0] + bo, acc[o][1] + bo,
                                     acc[o][2] + bo, acc[o][3] + bo);
        const size_t idx = ((((size_t)n * 10 + o) * 10 + z) * 128 + y) * 128 + x0;
        *(float4*)(out + idx) = v;
    }
}

extern "C" void kernel_launch(void* const* d_in, const int* in_sizes, int n_in,
                              void* d_out, int out_size, void* d_ws, size_t ws_size,
                              hipStream_t stream) {
    const float* x    = (const float*)d_in[0];  // [32,10,128,128]
    const float* Wt   = (const float*)d_in[1];  // [10,10,5,5,5]
    const float* bias = (const float*)d_in[2];  // [10]
    float* out = (float*)d_out;                 // [32,10,10,128,128]

    dim3 grid(16, 10, 32);   // (row tiles, z, n) = 5120 blocks
    conv3d_diag_kernel<<<grid, BLOCK, 0, stream>>>(x, Wt, bias, out);
}